// Round 4
// baseline (48596.317 us; speedup 1.0000x reference)
//
#include <hip/hip_runtime.h>
#include <hip/hip_cooperative_groups.h>
#include <math.h>

namespace cg = cooperative_groups;

typedef __bf16 bf16;
typedef __attribute__((ext_vector_type(8))) __bf16 bf16x8;
typedef __attribute__((ext_vector_type(4))) float f32x4;

static constexpr int B = 256, L = 512, D = 64, P = 256, H = 512, M = 256, HOR = 9;
static constexpr int G = 2048;        // 4*H gate columns
static constexpr int K0 = P + H;      // 768  (layer0 K: emb | h0_prev)
static constexpr int K1 = 2 * H;      // 1024 (layer1 K: h0 | h1_prev)
static constexpr float EPS = 1e-5f;

#define MFMA(a, b, c) __builtin_amdgcn_mfma_f32_16x16x32_bf16((a), (b), (c), 0, 0, 0)

__device__ __forceinline__ float sigmoidf_(float x) { return 1.0f / (1.0f + expf(-x)); }
__device__ __forceinline__ float gelu_exact(float x) {
    return 0.5f * x * (1.0f + erff(x * 0.70710678118654752f));
}

// Accumulate one K-segment with 3 independent accumulator sets (ILP):
//   hh += Ahi*Bhi, hl += Ahi*Blo, lh += Alo*Bhi   (lo*lo dropped)
template <bool AL>
__device__ __forceinline__ void seg_accum(
    const bf16* __restrict__ ah, const bf16* __restrict__ al, long ldA,
    const bf16* __restrict__ bh, const bf16* __restrict__ bl, long ldB,
    int ksteps, f32x4 (&hh)[2][2], f32x4 (&hl)[2][2], f32x4 (&lh)[2][2])
{
    const long a1 = 16 * ldA;
    const long b1 = 512 * ldB;
#pragma unroll 4
    for (int s = 0; s < ksteps; ++s) {
        bf16x8 A0  = *(const bf16x8*)(ah);
        bf16x8 A1  = *(const bf16x8*)(ah + a1);
        bf16x8 B0h = *(const bf16x8*)(bh);
        bf16x8 B1h = *(const bf16x8*)(bh + b1);
        bf16x8 B0l = *(const bf16x8*)(bl);
        bf16x8 B1l = *(const bf16x8*)(bl + b1);
        hh[0][0] = MFMA(A0, B0h, hh[0][0]);
        hh[0][1] = MFMA(A0, B1h, hh[0][1]);
        hh[1][0] = MFMA(A1, B0h, hh[1][0]);
        hh[1][1] = MFMA(A1, B1h, hh[1][1]);
        hl[0][0] = MFMA(A0, B0l, hl[0][0]);
        hl[0][1] = MFMA(A0, B1l, hl[0][1]);
        hl[1][0] = MFMA(A1, B0l, hl[1][0]);
        hl[1][1] = MFMA(A1, B1l, hl[1][1]);
        if (AL) {
            bf16x8 A0l = *(const bf16x8*)(al);
            bf16x8 A1l = *(const bf16x8*)(al + a1);
            lh[0][0] = MFMA(A0l, B0h, lh[0][0]);
            lh[0][1] = MFMA(A0l, B1h, lh[0][1]);
            lh[1][0] = MFMA(A1l, B0h, lh[1][0]);
            lh[1][1] = MFMA(A1l, B1h, lh[1][1]);
        }
        ah += 32; al += 32; bh += 32; bl += 32;
    }
}

// ---------------------------------------------------------------------------
// emb = gelu(LN(x@Wp+bp)) -> bf16 hi/lo, T-MAJOR: [(t*B + b)*P + p]
// ---------------------------------------------------------------------------
__global__ __launch_bounds__(256) void emb_kernel(
    const float* __restrict__ x, const float* __restrict__ Wp,
    const float* __restrict__ bp, const float* __restrict__ gamma,
    const float* __restrict__ beta, bf16* __restrict__ ehi,
    bf16* __restrict__ elo, int use_elo)
{
    const int row = blockIdx.x;          // b*L + t
    const int b   = row >> 9;
    const int t   = row & (L - 1);
    const int p   = threadIdx.x;
    __shared__ float xs[D];
    __shared__ float red[P];

    if (p < D) xs[p] = x[(size_t)row * D + p];
    __syncthreads();

    float acc = bp[p];
#pragma unroll
    for (int k = 0; k < D; ++k) acc = fmaf(xs[k], Wp[k * P + p], acc);

    red[p] = acc;
    __syncthreads();
    for (int s = 128; s > 0; s >>= 1) { if (p < s) red[p] += red[p + s]; __syncthreads(); }
    const float mu = red[0] * (1.0f / (float)P);
    __syncthreads();
    const float d = acc - mu;
    red[p] = d * d;
    __syncthreads();
    for (int s = 128; s > 0; s >>= 1) { if (p < s) red[p] += red[p + s]; __syncthreads(); }
    const float var = red[0] * (1.0f / (float)P);

    const float v = gelu_exact(gamma[p] * d * rsqrtf(var + EPS) + beta[p]);
    const size_t o = ((size_t)t * B + b) * P + p;
    const bf16 hh = (bf16)v;
    ehi[o] = hh;
    if (use_elo) elo[o] = (bf16)(v - (float)hh);
}

// ---------------------------------------------------------------------------
// weight prep
// ---------------------------------------------------------------------------
__global__ __launch_bounds__(256) void prep_w0(
    const float* __restrict__ Wih0, const float* __restrict__ Whh0,
    bf16* __restrict__ hi, bf16* __restrict__ lo)
{
    const int k = blockIdx.x * 256 + threadIdx.x;   // grid.x = 3
    const int g = blockIdx.y;
    const float v = (k < P) ? Wih0[(size_t)g * P + k] : Whh0[(size_t)g * H + (k - P)];
    const bf16 h = (bf16)v;
    const size_t o = (size_t)g * K0 + k;
    hi[o] = h; lo[o] = (bf16)(v - (float)h);
}

__global__ __launch_bounds__(256) void prep_w1(
    const float* __restrict__ Wih1, const float* __restrict__ Whh1,
    bf16* __restrict__ hi, bf16* __restrict__ lo)
{
    const int k = blockIdx.x * 256 + threadIdx.x;   // grid.x = 4
    const int g = blockIdx.y;
    const float v = (k < H) ? Wih1[(size_t)g * H + k] : Whh1[(size_t)g * H + (k - H)];
    const bf16 h = (bf16)v;
    const size_t o = (size_t)g * K1 + k;
    hi[o] = h; lo[o] = (bf16)(v - (float)h);
}

__global__ __launch_bounds__(256) void prep_bias(
    const float* __restrict__ bih0, const float* __restrict__ bhh0,
    const float* __restrict__ bih1, const float* __restrict__ bhh1,
    float* __restrict__ bsum0, float* __restrict__ bsum1)
{
    const int g = blockIdx.x * 256 + threadIdx.x;   // grid.x = 8
    bsum0[g] = bih0[g] + bhh0[g];
    bsum1[g] = bih1[g] + bhh1[g];
}

// ---------------------------------------------------------------------------
// Persistent recurrence kernel (cooperative). 256 blocks x 256 threads,
// 1 block/CU. Loops t = 0..512; per tick:
//   blocks 0..127  : layer0 step t   (skipped at t=512)
//   blocks 128..255: layer1 step t-1 (skipped at t=0)
// then grid.sync(). Tile 64 batch x 64 gate-cols (16 j x 4 gates), 4 waves
// as 2x2, each wave 2x2 16x16x32 MFMA frags, 3-pass hi/lo split.
// h buffers: h0 writes buf[t&1], reads buf[1-(t&1)]; h1 reads buf[t&1],
// writes buf[1-(t&1)]. c0/c1 in-place (unique owner per element).
// ---------------------------------------------------------------------------
struct RArgs {
    int use_elo;
    const bf16 *ehi, *elo;
    const bf16 *W0hi, *W0lo, *W1hi, *W1lo;
    const float *bsum0, *bsum1;
    bf16 *h0hi[2], *h0lo[2], *h1hi[2], *h1lo[2];
    float *c0, *c1;
};

__global__ __launch_bounds__(256, 1) void recurrence_kernel(RArgs a)
{
    cg::grid_group grid = cg::this_grid();

    const int layer = blockIdx.x >> 7;
    const int idx = blockIdx.x & 127;
    const int mg = idx >> 5, ng = idx & 31;
    const int bm0 = mg * 64, j0 = ng * 16;

    const int tid  = threadIdx.x;
    const int lane = tid & 63, wid = tid >> 6;
    const int wm = wid >> 1, wn = wid & 1;
    const int rA   = lane & 15;
    const int koff = (lane >> 4) * 8;

    __shared__ float Gs[64][68];

    const long arow = bm0 + wm * 32 + rA;
    const size_t ho = (size_t)arow * H + koff;

    // loop-invariant weight fragment pointers
    const bf16* w0h = a.W0hi + (size_t)((wn * 2) * 512 + j0 + rA) * K0 + koff;
    const bf16* w0l = a.W0lo + (size_t)((wn * 2) * 512 + j0 + rA) * K0 + koff;
    const bf16* w1h = a.W1hi + (size_t)((wn * 2) * 512 + j0 + rA) * K1 + koff;
    const bf16* w1l = a.W1lo + (size_t)((wn * 2) * 512 + j0 + rA) * K1 + koff;

    const float* bs = layer ? a.bsum1 : a.bsum0;
    float* cc = layer ? a.c1 : a.c0;

    for (int t = 0; t <= L; ++t) {
        const int p0 = t & 1;
        const bool active = layer ? (t >= 1) : (t < L);

        if (active) {
            f32x4 hh[2][2] = {}, hl[2][2] = {}, lh[2][2] = {};

            if (layer == 0) {
                const bf16* h0r_hi = a.h0hi[1 - p0];
                const bf16* h0r_lo = a.h0lo[1 - p0];
                // segment 1: emb_t (K = 256)
                const size_t eo = ((size_t)t * B + arow) * P + koff;
                if (a.use_elo)
                    seg_accum<true >(a.ehi + eo, a.elo + eo, P, w0h, w0l, K0, P / 32, hh, hl, lh);
                else
                    seg_accum<false>(a.ehi + eo, a.elo + eo, P, w0h, w0l, K0, P / 32, hh, hl, lh);
                // segment 2: h0_prev (K = 512)
                seg_accum<true>(h0r_hi + ho, h0r_lo + ho, H, w0h + P, w0l + P, K0, H / 32, hh, hl, lh);
            } else {
                const bf16* h0r_hi = a.h0hi[1 - p0];   // h0[t-1]
                const bf16* h0r_lo = a.h0lo[1 - p0];
                const bf16* h1r_hi = a.h1hi[p0];       // h1[t-2]
                const bf16* h1r_lo = a.h1lo[p0];
                seg_accum<true>(h0r_hi + ho, h0r_lo + ho, H, w1h, w1l, K1, H / 32, hh, hl, lh);
                seg_accum<true>(h1r_hi + ho, h1r_lo + ho, H, w1h + H, w1l + H, K1, H / 32, hh, hl, lh);
            }

            // park gates in LDS (C/D: col = lane&15, row = (lane>>4)*4 + reg)
#pragma unroll
            for (int mi = 0; mi < 2; ++mi)
#pragma unroll
                for (int ni = 0; ni < 2; ++ni) {
                    const int ml = wm * 32 + mi * 16 + (lane >> 4) * 4;
                    const int nl = wn * 32 + ni * 16 + (lane & 15);
#pragma unroll
                    for (int r = 0; r < 4; ++r)
                        Gs[ml + r][nl] = hh[mi][ni][r] + hl[mi][ni][r] + lh[mi][ni][r];
                }
            __syncthreads();

            bf16* hwh = layer ? a.h1hi[1 - p0] : a.h0hi[p0];
            bf16* hwl = layer ? a.h1lo[1 - p0] : a.h0lo[p0];

#pragma unroll
            for (int p = 0; p < 4; ++p) {
                const int pr = tid + p * 256;
                const int m = pr >> 4, jj = pr & 15;
                const int j = j0 + jj;
                const float iraw = Gs[m][jj]      + bs[j];
                const float fraw = Gs[m][16 + jj] + bs[512 + j];
                const float graw = Gs[m][32 + jj] + bs[1024 + j];
                const float oraw = Gs[m][48 + jj] + bs[1536 + j];
                const size_t ix = (size_t)(bm0 + m) * H + j;
                const float cv = sigmoidf_(fraw) * cc[ix] + sigmoidf_(iraw) * tanhf(graw);
                cc[ix] = cv;
                const float hv = sigmoidf_(oraw) * tanhf(cv);
                const bf16 hb = (bf16)hv;
                hwh[ix] = hb;
                hwl[ix] = (bf16)(hv - (float)hb);
            }
            __threadfence();
        }

        grid.sync();
    }
}

// ---------------------------------------------------------------------------
// head: per batch row b, j = joint_index[b]
// ---------------------------------------------------------------------------
__global__ __launch_bounds__(256) void head_kernel(
    const bf16* __restrict__ h_hi, const bf16* __restrict__ h_lo,
    const int* __restrict__ joint_index,
    const float* __restrict__ Wh1, const float* __restrict__ bh1,
    const float* __restrict__ Wh2, const float* __restrict__ bh2,
    float* __restrict__ out)
{
    const int b = blockIdx.x;
    const int t = threadIdx.x;
    const int j = joint_index[b];
    __shared__ float hs[H];
    __shared__ float zs[M];

    hs[t]       = (float)h_hi[(size_t)b * H + t]       + (float)h_lo[(size_t)b * H + t];
    hs[t + 256] = (float)h_hi[(size_t)b * H + 256 + t] + (float)h_lo[(size_t)b * H + 256 + t];
    __syncthreads();

    float acc = bh1[j * M + t];
    const float* w = Wh1 + (size_t)j * H * M + t;
#pragma unroll 8
    for (int k = 0; k < H; ++k) acc = fmaf(hs[k], w[(size_t)k * M], acc);

    zs[t] = gelu_exact(acc);
    __syncthreads();

    if (t < HOR) {
        float a = bh2[j * HOR + t];
        const float* w2 = Wh2 + (size_t)j * M * HOR + t;
        for (int m = 0; m < M; ++m) a = fmaf(zs[m], w2[(size_t)m * HOR], a);
        out[(size_t)b * HOR + t] = a;
    }
}

// ---------------------------------------------------------------------------
extern "C" void kernel_launch(void* const* d_in, const int* in_sizes, int n_in,
                              void* d_out, int out_size, void* d_ws, size_t ws_size,
                              hipStream_t stream)
{
    const float* x     = (const float*)d_in[0];
    const int*   joint = (const int*)  d_in[1];
    const float* Wp    = (const float*)d_in[2];
    const float* bp    = (const float*)d_in[3];
    const float* gamma = (const float*)d_in[4];
    const float* beta  = (const float*)d_in[5];
    const float* Wih0  = (const float*)d_in[6];
    const float* Whh0  = (const float*)d_in[7];
    const float* bih0  = (const float*)d_in[8];
    const float* bhh0  = (const float*)d_in[9];
    const float* Wih1  = (const float*)d_in[10];
    const float* Whh1  = (const float*)d_in[11];
    const float* bih1  = (const float*)d_in[12];
    const float* bhh1  = (const float*)d_in[13];
    const float* Wh1   = (const float*)d_in[14];
    const float* bh1   = (const float*)d_in[15];
    const float* Wh2   = (const float*)d_in[16];
    const float* bh2   = (const float*)d_in[17];
    float* out = (float*)d_out;

    char* base = (char*)d_ws;
    size_t off = 0;
    auto take = [&](size_t nbytes) -> void* {
        void* p = base + off;
        off = (off + nbytes + 255) & ~(size_t)255;
        return p;
    };

    RArgs a;
    a.W0hi = (bf16*)take((size_t)G * K0 * 2);
    a.W0lo = (bf16*)take((size_t)G * K0 * 2);
    a.W1hi = (bf16*)take((size_t)G * K1 * 2);
    a.W1lo = (bf16*)take((size_t)G * K1 * 2);
    a.bsum0 = (float*)take(G * 4);
    a.bsum1 = (float*)take(G * 4);

    const size_t states_off = off;
    for (int i = 0; i < 2; ++i) a.h0hi[i] = (bf16*)take((size_t)B * H * 2);
    for (int i = 0; i < 2; ++i) a.h0lo[i] = (bf16*)take((size_t)B * H * 2);
    for (int i = 0; i < 2; ++i) a.h1hi[i] = (bf16*)take((size_t)B * H * 2);
    for (int i = 0; i < 2; ++i) a.h1lo[i] = (bf16*)take((size_t)B * H * 2);
    a.c0 = (float*)take((size_t)B * H * 4);
    a.c1 = (float*)take((size_t)B * H * 4);
    const size_t states_bytes = off - states_off;

    bf16* ehi = (bf16*)take((size_t)L * B * P * 2);
    bf16* elo = (bf16*)take((size_t)L * B * P * 2);
    a.use_elo = (off <= ws_size) ? 1 : 0;
    if (!a.use_elo) elo = ehi;   // never read/written when use_elo==0
    a.ehi = ehi; a.elo = elo;

    prep_w0<<<dim3(3, G), 256, 0, stream>>>(Wih0, Whh0, (bf16*)a.W0hi, (bf16*)a.W0lo);
    prep_w1<<<dim3(4, G), 256, 0, stream>>>(Wih1, Whh1, (bf16*)a.W1hi, (bf16*)a.W1lo);
    prep_bias<<<8, 256, 0, stream>>>(bih0, bhh0, bih1, bhh1, (float*)a.bsum0, (float*)a.bsum1);
    hipMemsetAsync(base + states_off, 0, states_bytes, stream);
    emb_kernel<<<B * L, 256, 0, stream>>>(x, Wp, bp, gamma, beta, ehi, elo, a.use_elo);

    void* params[] = { &a };
    hipLaunchCooperativeKernel((void*)recurrence_kernel, dim3(256), dim3(256),
                               params, 0, stream);

    // final h1 (step 511) written at tick t=512 into buf[1-(512&1)] = buf 1
    head_kernel<<<B, 256, 0, stream>>>(a.h1hi[1], a.h1lo[1], joint, Wh1, bh1, Wh2, bh2, out);
}

// Round 5
// 30111.536 us; speedup vs baseline: 1.6139x; 1.6139x over previous
//
#include <hip/hip_runtime.h>
#include <math.h>

typedef __bf16 bf16;
typedef __attribute__((ext_vector_type(8))) __bf16 bf16x8;
typedef __attribute__((ext_vector_type(4))) float f32x4;

static constexpr int B = 256, L = 512, D = 64, P = 256, H = 512, M = 256, HOR = 9;
static constexpr int G = 2048;        // 4*H gate columns
static constexpr int K0 = P + H;      // 768  (layer0 K: emb | h0_prev)
static constexpr int K1 = 2 * H;      // 1024 (layer1 K: h0 | h1_prev)
static constexpr float EPS = 1e-5f;

#define MFMA(a, b, c) __builtin_amdgcn_mfma_f32_16x16x32_bf16((a), (b), (c), 0, 0, 0)

__device__ __forceinline__ float sigmoidf_(float x) { return 1.0f / (1.0f + expf(-x)); }
__device__ __forceinline__ float gelu_exact(float x) {
    return 0.5f * x * (1.0f + erff(x * 0.70710678118654752f));
}

// Device-coherent 16B fragment load (2 x 8B agent-scope relaxed atomic loads
// -> global_load_dwordx2 sc1: reads through stale per-XCD L2 to the LLC,
// still pipelined by the compiler's normal vmcnt scoreboarding).
__device__ __forceinline__ bf16x8 cload(const bf16* p) {
    union { unsigned long long u[2]; bf16x8 v; } r;
    const unsigned long long* q = (const unsigned long long*)p;
    r.u[0] = __hip_atomic_load(q,     __ATOMIC_RELAXED, __HIP_MEMORY_SCOPE_AGENT);
    r.u[1] = __hip_atomic_load(q + 1, __ATOMIC_RELAXED, __HIP_MEMORY_SCOPE_AGENT);
    return r.v;
}

// Accumulate one K-segment with 3 independent accumulator sets (ILP):
//   hh += Ahi*Bhi, hl += Ahi*Blo, lh += Alo*Bhi   (lo*lo dropped)
// ACOH: A operand is cross-block state -> device-coherent loads.
template <bool AL, bool ACOH>
__device__ __forceinline__ void seg_accum(
    const bf16* __restrict__ ah, const bf16* __restrict__ al, long ldA,
    const bf16* __restrict__ bh, const bf16* __restrict__ bl, long ldB,
    int ksteps, f32x4 (&hh)[2][2], f32x4 (&hl)[2][2], f32x4 (&lh)[2][2])
{
    const long a1 = 16 * ldA;
    const long b1 = 512 * ldB;
#pragma unroll 4
    for (int s = 0; s < ksteps; ++s) {
        bf16x8 A0  = ACOH ? cload(ah)      : *(const bf16x8*)(ah);
        bf16x8 A1  = ACOH ? cload(ah + a1) : *(const bf16x8*)(ah + a1);
        bf16x8 B0h = *(const bf16x8*)(bh);
        bf16x8 B1h = *(const bf16x8*)(bh + b1);
        bf16x8 B0l = *(const bf16x8*)(bl);
        bf16x8 B1l = *(const bf16x8*)(bl + b1);
        hh[0][0] = MFMA(A0, B0h, hh[0][0]);
        hh[0][1] = MFMA(A0, B1h, hh[0][1]);
        hh[1][0] = MFMA(A1, B0h, hh[1][0]);
        hh[1][1] = MFMA(A1, B1h, hh[1][1]);
        hl[0][0] = MFMA(A0, B0l, hl[0][0]);
        hl[0][1] = MFMA(A0, B1l, hl[0][1]);
        hl[1][0] = MFMA(A1, B0l, hl[1][0]);
        hl[1][1] = MFMA(A1, B1l, hl[1][1]);
        if (AL) {
            bf16x8 A0l = ACOH ? cload(al)      : *(const bf16x8*)(al);
            bf16x8 A1l = ACOH ? cload(al + a1) : *(const bf16x8*)(al + a1);
            lh[0][0] = MFMA(A0l, B0h, lh[0][0]);
            lh[0][1] = MFMA(A0l, B1h, lh[0][1]);
            lh[1][0] = MFMA(A1l, B0h, lh[1][0]);
            lh[1][1] = MFMA(A1l, B1h, lh[1][1]);
        }
        ah += 32; al += 32; bh += 32; bl += 32;
    }
}

// ---------------------------------------------------------------------------
// emb = gelu(LN(x@Wp+bp)) -> bf16 hi/lo, T-MAJOR: [(t*B + b)*P + p]
// ---------------------------------------------------------------------------
__global__ __launch_bounds__(256) void emb_kernel(
    const float* __restrict__ x, const float* __restrict__ Wp,
    const float* __restrict__ bp, const float* __restrict__ gamma,
    const float* __restrict__ beta, bf16* __restrict__ ehi,
    bf16* __restrict__ elo, int use_elo)
{
    const int row = blockIdx.x;          // b*L + t
    const int b   = row >> 9;
    const int t   = row & (L - 1);
    const int p   = threadIdx.x;
    __shared__ float xs[D];
    __shared__ float red[P];

    if (p < D) xs[p] = x[(size_t)row * D + p];
    __syncthreads();

    float acc = bp[p];
#pragma unroll
    for (int k = 0; k < D; ++k) acc = fmaf(xs[k], Wp[k * P + p], acc);

    red[p] = acc;
    __syncthreads();
    for (int s = 128; s > 0; s >>= 1) { if (p < s) red[p] += red[p + s]; __syncthreads(); }
    const float mu = red[0] * (1.0f / (float)P);
    __syncthreads();
    const float d = acc - mu;
    red[p] = d * d;
    __syncthreads();
    for (int s = 128; s > 0; s >>= 1) { if (p < s) red[p] += red[p + s]; __syncthreads(); }
    const float var = red[0] * (1.0f / (float)P);

    const float v = gelu_exact(gamma[p] * d * rsqrtf(var + EPS) + beta[p]);
    const size_t o = ((size_t)t * B + b) * P + p;
    const bf16 hh = (bf16)v;
    ehi[o] = hh;
    if (use_elo) elo[o] = (bf16)(v - (float)hh);
}

// ---------------------------------------------------------------------------
// weight prep
// ---------------------------------------------------------------------------
__global__ __launch_bounds__(256) void prep_w0(
    const float* __restrict__ Wih0, const float* __restrict__ Whh0,
    bf16* __restrict__ hi, bf16* __restrict__ lo)
{
    const int k = blockIdx.x * 256 + threadIdx.x;   // grid.x = 3
    const int g = blockIdx.y;
    const float v = (k < P) ? Wih0[(size_t)g * P + k] : Whh0[(size_t)g * H + (k - P)];
    const bf16 h = (bf16)v;
    const size_t o = (size_t)g * K0 + k;
    hi[o] = h; lo[o] = (bf16)(v - (float)h);
}

__global__ __launch_bounds__(256) void prep_w1(
    const float* __restrict__ Wih1, const float* __restrict__ Whh1,
    bf16* __restrict__ hi, bf16* __restrict__ lo)
{
    const int k = blockIdx.x * 256 + threadIdx.x;   // grid.x = 4
    const int g = blockIdx.y;
    const float v = (k < H) ? Wih1[(size_t)g * H + k] : Whh1[(size_t)g * H + (k - H)];
    const bf16 h = (bf16)v;
    const size_t o = (size_t)g * K1 + k;
    hi[o] = h; lo[o] = (bf16)(v - (float)h);
}

__global__ __launch_bounds__(256) void prep_bias(
    const float* __restrict__ bih0, const float* __restrict__ bhh0,
    const float* __restrict__ bih1, const float* __restrict__ bhh1,
    float* __restrict__ bsum0, float* __restrict__ bsum1)
{
    const int g = blockIdx.x * 256 + threadIdx.x;   // grid.x = 8
    bsum0[g] = bih0[g] + bhh0[g];
    bsum1[g] = bih1[g] + bhh1[g];
}

// ---------------------------------------------------------------------------
// Persistent recurrence kernel. 256 blocks x 256 threads (cooperative launch
// for guaranteed co-residency, but NO cg::grid.sync -- custom barriers).
// Batch rows never mix across the recurrence, so row-group mg (64 rows)
// = 32 L0 blocks + 32 L1 blocks is a closed dependency set with its own
// 64-block barrier bar[mg] (monotone counter, release-add / relaxed-spin).
// Cross-block state (h0/h1 hi/lo) is read with agent-scope coherent loads;
// weights/emb/bias/c use normal cached loads -> per-XCD L2 stays warm.
// ---------------------------------------------------------------------------
struct RArgs {
    int use_elo;
    const bf16 *ehi, *elo;
    const bf16 *W0hi, *W0lo, *W1hi, *W1lo;
    const float *bsum0, *bsum1;
    bf16 *h0hi[2], *h0lo[2], *h1hi[2], *h1lo[2];
    float *c0, *c1;
    unsigned int* bar;    // 4 counters, 256B apart
};

__global__ __launch_bounds__(256, 1) void recurrence_kernel(RArgs a)
{
    const int layer = blockIdx.x >> 7;
    const int idx = blockIdx.x & 127;
    const int mg = idx >> 5, ng = idx & 31;
    const int bm0 = mg * 64, j0 = ng * 16;

    const int tid  = threadIdx.x;
    const int lane = tid & 63, wid = tid >> 6;
    const int wm = wid >> 1, wn = wid & 1;
    const int rA   = lane & 15;
    const int koff = (lane >> 4) * 8;

    __shared__ float Gs[64][68];

    unsigned int* bar = a.bar + mg * 64;   // 256B-separated counters

    const long arow = bm0 + wm * 32 + rA;
    const size_t ho = (size_t)arow * H + koff;

    // loop-invariant weight fragment pointers
    const bf16* w0h = a.W0hi + (size_t)((wn * 2) * 512 + j0 + rA) * K0 + koff;
    const bf16* w0l = a.W0lo + (size_t)((wn * 2) * 512 + j0 + rA) * K0 + koff;
    const bf16* w1h = a.W1hi + (size_t)((wn * 2) * 512 + j0 + rA) * K1 + koff;
    const bf16* w1l = a.W1lo + (size_t)((wn * 2) * 512 + j0 + rA) * K1 + koff;

    const float* bs = layer ? a.bsum1 : a.bsum0;
    float* cc = layer ? a.c1 : a.c0;

    for (int t = 0; t <= L; ++t) {
        const int p0 = t & 1;
        const bool active = layer ? (t >= 1) : (t < L);

        if (active) {
            f32x4 hh[2][2] = {}, hl[2][2] = {}, lh[2][2] = {};

            if (layer == 0) {
                const bf16* h0r_hi = a.h0hi[1 - p0];
                const bf16* h0r_lo = a.h0lo[1 - p0];
                // segment 1: emb_t (K = 256), read-only -> normal loads
                const size_t eo = ((size_t)t * B + arow) * P + koff;
                if (a.use_elo)
                    seg_accum<true , false>(a.ehi + eo, a.elo + eo, P, w0h, w0l, K0, P / 32, hh, hl, lh);
                else
                    seg_accum<false, false>(a.ehi + eo, a.elo + eo, P, w0h, w0l, K0, P / 32, hh, hl, lh);
                // segment 2: h0_prev (K = 512), cross-block state -> coherent
                seg_accum<true, true>(h0r_hi + ho, h0r_lo + ho, H, w0h + P, w0l + P, K0, H / 32, hh, hl, lh);
            } else {
                const bf16* h0r_hi = a.h0hi[1 - p0];   // h0[t-1]
                const bf16* h0r_lo = a.h0lo[1 - p0];
                const bf16* h1r_hi = a.h1hi[p0];       // h1[t-2]
                const bf16* h1r_lo = a.h1lo[p0];
                seg_accum<true, true>(h0r_hi + ho, h0r_lo + ho, H, w1h, w1l, K1, H / 32, hh, hl, lh);
                seg_accum<true, true>(h1r_hi + ho, h1r_lo + ho, H, w1h + H, w1l + H, K1, H / 32, hh, hl, lh);
            }

            // park gates in LDS (C/D: col = lane&15, row = (lane>>4)*4 + reg)
#pragma unroll
            for (int mi = 0; mi < 2; ++mi)
#pragma unroll
                for (int ni = 0; ni < 2; ++ni) {
                    const int ml = wm * 32 + mi * 16 + (lane >> 4) * 4;
                    const int nl = wn * 32 + ni * 16 + (lane & 15);
#pragma unroll
                    for (int r = 0; r < 4; ++r)
                        Gs[ml + r][nl] = hh[mi][ni][r] + hl[mi][ni][r] + lh[mi][ni][r];
                }
            __syncthreads();

            bf16* hwh = layer ? a.h1hi[1 - p0] : a.h0hi[p0];
            bf16* hwl = layer ? a.h1lo[1 - p0] : a.h0lo[p0];

#pragma unroll
            for (int p = 0; p < 4; ++p) {
                const int pr = tid + p * 256;
                const int m = pr >> 4, jj = pr & 15;
                const int j = j0 + jj;
                const float iraw = Gs[m][jj]      + bs[j];
                const float fraw = Gs[m][16 + jj] + bs[512 + j];
                const float graw = Gs[m][32 + jj] + bs[1024 + j];
                const float oraw = Gs[m][48 + jj] + bs[1536 + j];
                const size_t ix = (size_t)(bm0 + m) * H + j;
                const float cv = sigmoidf_(fraw) * cc[ix] + sigmoidf_(iraw) * tanhf(graw);
                cc[ix] = cv;
                const float hv = sigmoidf_(oraw) * tanhf(cv);
                const bf16 hb = (bf16)hv;
                hwh[ix] = hb;
                hwl[ix] = (bf16)(hv - (float)hb);
            }
        }

        // ---- group barrier: 64 blocks of row-group mg ----
        __syncthreads();   // all threads' stores issued before arrive
        if (tid == 0) {
            // release-add: waitcnt + buffer_wbl2 (dirty-only writeback) + add
            __hip_atomic_fetch_add(bar, 1u, __ATOMIC_RELEASE, __HIP_MEMORY_SCOPE_AGENT);
            const unsigned int target = 64u * (unsigned)(t + 1);
            while (__hip_atomic_load(bar, __ATOMIC_RELAXED, __HIP_MEMORY_SCOPE_AGENT) < target)
                __builtin_amdgcn_s_sleep(1);
        }
        __syncthreads();   // rest of block waits for spinner
    }
}

// ---------------------------------------------------------------------------
// head: per batch row b, j = joint_index[b]
// ---------------------------------------------------------------------------
__global__ __launch_bounds__(256) void head_kernel(
    const bf16* __restrict__ h_hi, const bf16* __restrict__ h_lo,
    const int* __restrict__ joint_index,
    const float* __restrict__ Wh1, const float* __restrict__ bh1,
    const float* __restrict__ Wh2, const float* __restrict__ bh2,
    float* __restrict__ out)
{
    const int b = blockIdx.x;
    const int t = threadIdx.x;
    const int j = joint_index[b];
    __shared__ float hs[H];
    __shared__ float zs[M];

    hs[t]       = (float)h_hi[(size_t)b * H + t]       + (float)h_lo[(size_t)b * H + t];
    hs[t + 256] = (float)h_hi[(size_t)b * H + 256 + t] + (float)h_lo[(size_t)b * H + 256 + t];
    __syncthreads();

    float acc = bh1[j * M + t];
    const float* w = Wh1 + (size_t)j * H * M + t;
#pragma unroll 8
    for (int k = 0; k < H; ++k) acc = fmaf(hs[k], w[(size_t)k * M], acc);

    zs[t] = gelu_exact(acc);
    __syncthreads();

    if (t < HOR) {
        float a = bh2[j * HOR + t];
        const float* w2 = Wh2 + (size_t)j * M * HOR + t;
        for (int m = 0; m < M; ++m) a = fmaf(zs[m], w2[(size_t)m * HOR], a);
        out[(size_t)b * HOR + t] = a;
    }
}

// ---------------------------------------------------------------------------
extern "C" void kernel_launch(void* const* d_in, const int* in_sizes, int n_in,
                              void* d_out, int out_size, void* d_ws, size_t ws_size,
                              hipStream_t stream)
{
    const float* x     = (const float*)d_in[0];
    const int*   joint = (const int*)  d_in[1];
    const float* Wp    = (const float*)d_in[2];
    const float* bp    = (const float*)d_in[3];
    const float* gamma = (const float*)d_in[4];
    const float* beta  = (const float*)d_in[5];
    const float* Wih0  = (const float*)d_in[6];
    const float* Whh0  = (const float*)d_in[7];
    const float* bih0  = (const float*)d_in[8];
    const float* bhh0  = (const float*)d_in[9];
    const float* Wih1  = (const float*)d_in[10];
    const float* Whh1  = (const float*)d_in[11];
    const float* bih1  = (const float*)d_in[12];
    const float* bhh1  = (const float*)d_in[13];
    const float* Wh1   = (const float*)d_in[14];
    const float* bh1   = (const float*)d_in[15];
    const float* Wh2   = (const float*)d_in[16];
    const float* bh2   = (const float*)d_in[17];
    float* out = (float*)d_out;

    char* base = (char*)d_ws;
    size_t off = 0;
    auto take = [&](size_t nbytes) -> void* {
        void* p = base + off;
        off = (off + nbytes + 255) & ~(size_t)255;
        return p;
    };

    RArgs a;
    a.W0hi = (bf16*)take((size_t)G * K0 * 2);
    a.W0lo = (bf16*)take((size_t)G * K0 * 2);
    a.W1hi = (bf16*)take((size_t)G * K1 * 2);
    a.W1lo = (bf16*)take((size_t)G * K1 * 2);
    a.bsum0 = (float*)take(G * 4);
    a.bsum1 = (float*)take(G * 4);

    const size_t states_off = off;
    for (int i = 0; i < 2; ++i) a.h0hi[i] = (bf16*)take((size_t)B * H * 2);
    for (int i = 0; i < 2; ++i) a.h0lo[i] = (bf16*)take((size_t)B * H * 2);
    for (int i = 0; i < 2; ++i) a.h1hi[i] = (bf16*)take((size_t)B * H * 2);
    for (int i = 0; i < 2; ++i) a.h1lo[i] = (bf16*)take((size_t)B * H * 2);
    a.c0 = (float*)take((size_t)B * H * 4);
    a.c1 = (float*)take((size_t)B * H * 4);
    a.bar = (unsigned int*)take(4 * 256);
    const size_t states_bytes = off - states_off;   // includes bar -> zeroed

    bf16* ehi = (bf16*)take((size_t)L * B * P * 2);
    bf16* elo = (bf16*)take((size_t)L * B * P * 2);
    a.use_elo = (off <= ws_size) ? 1 : 0;
    if (!a.use_elo) elo = ehi;   // never read/written when use_elo==0
    a.ehi = ehi; a.elo = elo;

    prep_w0<<<dim3(3, G), 256, 0, stream>>>(Wih0, Whh0, (bf16*)a.W0hi, (bf16*)a.W0lo);
    prep_w1<<<dim3(4, G), 256, 0, stream>>>(Wih1, Whh1, (bf16*)a.W1hi, (bf16*)a.W1lo);
    prep_bias<<<8, 256, 0, stream>>>(bih0, bhh0, bih1, bhh1, (float*)a.bsum0, (float*)a.bsum1);
    hipMemsetAsync(base + states_off, 0, states_bytes, stream);
    emb_kernel<<<B * L, 256, 0, stream>>>(x, Wp, bp, gamma, beta, ehi, elo, a.use_elo);

    void* params[] = { &a };
    hipLaunchCooperativeKernel((void*)recurrence_kernel, dim3(256), dim3(256),
                               params, 0, stream);

    // final h1 (step 511) written at tick t=512 into buf[1-(512&1)] = buf 1
    head_kernel<<<B, 256, 0, stream>>>(a.h1hi[1], a.h1lo[1], joint, Wh1, bh1, Wh2, bh2, out);
}

// Round 6
// 25358.627 us; speedup vs baseline: 1.9164x; 1.1874x over previous
//
#include <hip/hip_runtime.h>
#include <math.h>

typedef __bf16 bf16;
typedef __attribute__((ext_vector_type(8))) __bf16 bf16x8;
typedef __attribute__((ext_vector_type(4))) float f32x4;

static constexpr int B = 256, L = 512, D = 64, P = 256, H = 512, M = 256, HOR = 9;
static constexpr int G = 2048;        // 4*H gate columns
static constexpr int K0 = P + H;      // 768  (layer0 K: emb | h0_prev)
static constexpr int K1 = 2 * H;      // 1024 (layer1 K: h0 | h1_prev)
static constexpr float EPS = 1e-5f;

#define MFMA(a, b, c) __builtin_amdgcn_mfma_f32_16x16x32_bf16((a), (b), (c), 0, 0, 0)

__device__ __forceinline__ float sigmoidf_(float x) { return 1.0f / (1.0f + expf(-x)); }
__device__ __forceinline__ float gelu_exact(float x) {
    return 0.5f * x * (1.0f + erff(x * 0.70710678118654752f));
}

// Device-coherent 16B fragment load (2 x 8B agent-scope relaxed atomic loads
// -> sc1 loads: bypass stale per-XCD L2/L1, read the LLC, still pipelined by
// normal vmcnt scoreboarding).
__device__ __forceinline__ bf16x8 cload(const bf16* p) {
    union { unsigned long long u[2]; bf16x8 v; } r;
    const unsigned long long* q = (const unsigned long long*)p;
    r.u[0] = __hip_atomic_load(q,     __ATOMIC_RELAXED, __HIP_MEMORY_SCOPE_AGENT);
    r.u[1] = __hip_atomic_load(q + 1, __ATOMIC_RELAXED, __HIP_MEMORY_SCOPE_AGENT);
    return r.v;
}

// Accumulate one K-segment with 3 independent accumulator sets (ILP):
//   hh += Ahi*Bhi, hl += Ahi*Blo, lh += Alo*Bhi   (lo x lo dropped)
// ACOH: A operand is cross-block state -> device-coherent loads.
template <bool AL, bool ACOH>
__device__ __forceinline__ void seg_accum(
    const bf16* __restrict__ ah, const bf16* __restrict__ al, long ldA,
    const bf16* __restrict__ bh, const bf16* __restrict__ bl, long ldB,
    int ksteps, f32x4 (&hh)[2][2], f32x4 (&hl)[2][2], f32x4 (&lh)[2][2])
{
    const long a1 = 16 * ldA;
    const long b1 = 512 * ldB;
#pragma unroll 4
    for (int s = 0; s < ksteps; ++s) {
        bf16x8 A0  = ACOH ? cload(ah)      : *(const bf16x8*)(ah);
        bf16x8 A1  = ACOH ? cload(ah + a1) : *(const bf16x8*)(ah + a1);
        bf16x8 B0h = *(const bf16x8*)(bh);
        bf16x8 B1h = *(const bf16x8*)(bh + b1);
        bf16x8 B0l = *(const bf16x8*)(bl);
        bf16x8 B1l = *(const bf16x8*)(bl + b1);
        hh[0][0] = MFMA(A0, B0h, hh[0][0]);
        hh[0][1] = MFMA(A0, B1h, hh[0][1]);
        hh[1][0] = MFMA(A1, B0h, hh[1][0]);
        hh[1][1] = MFMA(A1, B1h, hh[1][1]);
        hl[0][0] = MFMA(A0, B0l, hl[0][0]);
        hl[0][1] = MFMA(A0, B1l, hl[0][1]);
        hl[1][0] = MFMA(A1, B0l, hl[1][0]);
        hl[1][1] = MFMA(A1, B1l, hl[1][1]);
        if (AL) {
            bf16x8 A0l = ACOH ? cload(al)      : *(const bf16x8*)(al);
            bf16x8 A1l = ACOH ? cload(al + a1) : *(const bf16x8*)(al + a1);
            lh[0][0] = MFMA(A0l, B0h, lh[0][0]);
            lh[0][1] = MFMA(A0l, B1h, lh[0][1]);
            lh[1][0] = MFMA(A1l, B0h, lh[1][0]);
            lh[1][1] = MFMA(A1l, B1h, lh[1][1]);
        }
        ah += 32; al += 32; bh += 32; bl += 32;
    }
}

// ---------------------------------------------------------------------------
// emb = gelu(LN(x@Wp+bp)) -> bf16 hi/lo, T-MAJOR: [(t*B + b)*P + p]
// ---------------------------------------------------------------------------
__global__ __launch_bounds__(256) void emb_kernel(
    const float* __restrict__ x, const float* __restrict__ Wp,
    const float* __restrict__ bp, const float* __restrict__ gamma,
    const float* __restrict__ beta, bf16* __restrict__ ehi,
    bf16* __restrict__ elo, int use_elo)
{
    const int row = blockIdx.x;          // b*L + t
    const int b   = row >> 9;
    const int t   = row & (L - 1);
    const int p   = threadIdx.x;
    __shared__ float xs[D];
    __shared__ float red[P];

    if (p < D) xs[p] = x[(size_t)row * D + p];
    __syncthreads();

    float acc = bp[p];
#pragma unroll
    for (int k = 0; k < D; ++k) acc = fmaf(xs[k], Wp[k * P + p], acc);

    red[p] = acc;
    __syncthreads();
    for (int s = 128; s > 0; s >>= 1) { if (p < s) red[p] += red[p + s]; __syncthreads(); }
    const float mu = red[0] * (1.0f / (float)P);
    __syncthreads();
    const float d = acc - mu;
    red[p] = d * d;
    __syncthreads();
    for (int s = 128; s > 0; s >>= 1) { if (p < s) red[p] += red[p + s]; __syncthreads(); }
    const float var = red[0] * (1.0f / (float)P);

    const float v = gelu_exact(gamma[p] * d * rsqrtf(var + EPS) + beta[p]);
    const size_t o = ((size_t)t * B + b) * P + p;
    const bf16 hh = (bf16)v;
    ehi[o] = hh;
    if (use_elo) elo[o] = (bf16)(v - (float)hh);
}

// ---------------------------------------------------------------------------
// weight prep
// ---------------------------------------------------------------------------
__global__ __launch_bounds__(256) void prep_w0(
    const float* __restrict__ Wih0, const float* __restrict__ Whh0,
    bf16* __restrict__ hi, bf16* __restrict__ lo)
{
    const int k = blockIdx.x * 256 + threadIdx.x;   // grid.x = 3
    const int g = blockIdx.y;
    const float v = (k < P) ? Wih0[(size_t)g * P + k] : Whh0[(size_t)g * H + (k - P)];
    const bf16 h = (bf16)v;
    const size_t o = (size_t)g * K0 + k;
    hi[o] = h; lo[o] = (bf16)(v - (float)h);
}

__global__ __launch_bounds__(256) void prep_w1(
    const float* __restrict__ Wih1, const float* __restrict__ Whh1,
    bf16* __restrict__ hi, bf16* __restrict__ lo)
{
    const int k = blockIdx.x * 256 + threadIdx.x;   // grid.x = 4
    const int g = blockIdx.y;
    const float v = (k < H) ? Wih1[(size_t)g * H + k] : Whh1[(size_t)g * H + (k - H)];
    const bf16 h = (bf16)v;
    const size_t o = (size_t)g * K1 + k;
    hi[o] = h; lo[o] = (bf16)(v - (float)h);
}

__global__ __launch_bounds__(256) void prep_bias(
    const float* __restrict__ bih0, const float* __restrict__ bhh0,
    const float* __restrict__ bih1, const float* __restrict__ bhh1,
    float* __restrict__ bsum0, float* __restrict__ bsum1)
{
    const int g = blockIdx.x * 256 + threadIdx.x;   // grid.x = 8
    bsum0[g] = bih0[g] + bhh0[g];
    bsum1[g] = bih1[g] + bhh1[g];
}

// ---------------------------------------------------------------------------
// Persistent recurrence kernel, 256 blocks x 256 threads (cooperative launch
// for co-residency; custom per-row-group barriers).
// KEY change vs R5: h state is WRITTEN with agent-scope relaxed atomic stores
// (write-through to LLC, no dirty L2) so the barrier needs NO cache
// maintenance: __syncthreads() drains vmcnt (stores visible at LLC), then a
// RELAXED agent fetch_add + relaxed spin. No buffer_wbl2, no buffer_inv.
// c lives in 4 registers/thread for the whole loop (block->tile binding is
// tick-invariant); biases hoisted to registers.
// ---------------------------------------------------------------------------
struct RArgs {
    int use_elo;
    const bf16 *ehi, *elo;
    const bf16 *W0hi, *W0lo, *W1hi, *W1lo;
    const float *bsum0, *bsum1;
    bf16 *h0hi[2], *h0lo[2], *h1hi[2], *h1lo[2];
    unsigned int* bar;    // 4 counters, 256B apart
};

__global__ __launch_bounds__(256, 1) void recurrence_kernel(RArgs a)
{
    const int layer = blockIdx.x >> 7;
    const int idx = blockIdx.x & 127;
    const int mg = idx >> 5, ng = idx & 31;
    const int bm0 = mg * 64, j0 = ng * 16;

    const int tid  = threadIdx.x;
    const int lane = tid & 63, wid = tid >> 6;
    const int wm = wid >> 1, wn = wid & 1;
    const int rA   = lane & 15;
    const int koff = (lane >> 4) * 8;

    __shared__ float Gs[64][69];

    unsigned int* bar = a.bar + mg * 64;   // 256B-separated counters

    const long arow = bm0 + wm * 32 + rA;
    const size_t ho = (size_t)arow * H + koff;

    // loop-invariant weight fragment pointers
    const bf16* w0h = a.W0hi + (size_t)((wn * 2) * 512 + j0 + rA) * K0 + koff;
    const bf16* w0l = a.W0lo + (size_t)((wn * 2) * 512 + j0 + rA) * K0 + koff;
    const bf16* w1h = a.W1hi + (size_t)((wn * 2) * 512 + j0 + rA) * K1 + koff;
    const bf16* w1l = a.W1lo + (size_t)((wn * 2) * 512 + j0 + rA) * K1 + koff;

    // epilogue ownership: thread -> (em, ej0..ej0+3), tick-invariant
    const int em  = tid >> 2;            // 0..63
    const int ej0 = (tid & 3) * 4;       // 0,4,8,12
    const size_t hix = (size_t)(bm0 + em) * H + j0 + ej0;   // 8B-aligned

    // hoist biases into registers
    const float* bs = layer ? a.bsum1 : a.bsum0;
    float bI[4], bF[4], bG[4], bO[4];
#pragma unroll
    for (int q = 0; q < 4; ++q) {
        bI[q] = bs[j0 + ej0 + q];
        bF[q] = bs[512 + j0 + ej0 + q];
        bG[q] = bs[1024 + j0 + ej0 + q];
        bO[q] = bs[1536 + j0 + ej0 + q];
    }
    float creg[4] = {0.f, 0.f, 0.f, 0.f};   // c never touches memory

    for (int t = 0; t <= L; ++t) {
        const int p0 = t & 1;
        const bool active = layer ? (t >= 1) : (t < L);

        if (active) {
            f32x4 hh[2][2] = {}, hl[2][2] = {}, lh[2][2] = {};

            if (layer == 0) {
                const bf16* h0r_hi = a.h0hi[1 - p0];
                const bf16* h0r_lo = a.h0lo[1 - p0];
                // segment 1: emb_t (K = 256), read-only -> normal loads
                const size_t eo = ((size_t)t * B + arow) * P + koff;
                if (a.use_elo)
                    seg_accum<true , false>(a.ehi + eo, a.elo + eo, P, w0h, w0l, K0, P / 32, hh, hl, lh);
                else
                    seg_accum<false, false>(a.ehi + eo, a.elo + eo, P, w0h, w0l, K0, P / 32, hh, hl, lh);
                // segment 2: h0_prev (K = 512), cross-block state -> coherent
                seg_accum<true, true>(h0r_hi + ho, h0r_lo + ho, H, w0h + P, w0l + P, K0, H / 32, hh, hl, lh);
            } else {
                const bf16* h0r_hi = a.h0hi[1 - p0];   // h0[t-1]
                const bf16* h0r_lo = a.h0lo[1 - p0];
                const bf16* h1r_hi = a.h1hi[p0];       // h1[t-2]
                const bf16* h1r_lo = a.h1lo[p0];
                seg_accum<true, true>(h0r_hi + ho, h0r_lo + ho, H, w1h, w1l, K1, H / 32, hh, hl, lh);
                seg_accum<true, true>(h1r_hi + ho, h1r_lo + ho, H, w1h + H, w1l + H, K1, H / 32, hh, hl, lh);
            }

            // park gates in LDS (C/D: col = lane&15, row = (lane>>4)*4 + reg)
#pragma unroll
            for (int mi = 0; mi < 2; ++mi)
#pragma unroll
                for (int ni = 0; ni < 2; ++ni) {
                    const int ml = wm * 32 + mi * 16 + (lane >> 4) * 4;
                    const int nl = wn * 32 + ni * 16 + (lane & 15);
#pragma unroll
                    for (int r = 0; r < 4; ++r)
                        Gs[ml + r][nl] = hh[mi][ni][r] + hl[mi][ni][r] + lh[mi][ni][r];
                }
            __syncthreads();

            bf16* hwh = layer ? a.h1hi[1 - p0] : a.h0hi[p0];
            bf16* hwl = layer ? a.h1lo[1 - p0] : a.h0lo[p0];

            union { unsigned long long u; bf16 b[4]; } phi, plo;
#pragma unroll
            for (int q = 0; q < 4; ++q) {
                const float iraw = Gs[em][ej0 + q]      + bI[q];
                const float fraw = Gs[em][16 + ej0 + q] + bF[q];
                const float graw = Gs[em][32 + ej0 + q] + bG[q];
                const float oraw = Gs[em][48 + ej0 + q] + bO[q];
                const float cv = sigmoidf_(fraw) * creg[q] + sigmoidf_(iraw) * tanhf(graw);
                creg[q] = cv;
                const float hv = sigmoidf_(oraw) * tanhf(cv);
                const bf16 hb = (bf16)hv;
                phi.b[q] = hb;
                plo.b[q] = (bf16)(hv - (float)hb);
            }
            // write-through to LLC (sc1): no dirty L2 line -> no wbl2 needed
            __hip_atomic_store((unsigned long long*)(hwh + hix), phi.u,
                               __ATOMIC_RELAXED, __HIP_MEMORY_SCOPE_AGENT);
            __hip_atomic_store((unsigned long long*)(hwl + hix), plo.u,
                               __ATOMIC_RELAXED, __HIP_MEMORY_SCOPE_AGENT);
        }

        // ---- group barrier: 64 blocks of row-group mg; zero cache ops ----
        __syncthreads();   // drains each wave's vmcnt -> sc1 stores are in LLC
        if (tid == 0) {
            __hip_atomic_fetch_add(bar, 1u, __ATOMIC_RELAXED, __HIP_MEMORY_SCOPE_AGENT);
            const unsigned int target = 64u * (unsigned)(t + 1);
            while (__hip_atomic_load(bar, __ATOMIC_RELAXED, __HIP_MEMORY_SCOPE_AGENT) < target)
                __builtin_amdgcn_s_sleep(1);
        }
        __syncthreads();   // rest of block waits for spinner
    }
}

// ---------------------------------------------------------------------------
// head: per batch row b, j = joint_index[b]
// ---------------------------------------------------------------------------
__global__ __launch_bounds__(256) void head_kernel(
    const bf16* __restrict__ h_hi, const bf16* __restrict__ h_lo,
    const int* __restrict__ joint_index,
    const float* __restrict__ Wh1, const float* __restrict__ bh1,
    const float* __restrict__ Wh2, const float* __restrict__ bh2,
    float* __restrict__ out)
{
    const int b = blockIdx.x;
    const int t = threadIdx.x;
    const int j = joint_index[b];
    __shared__ float hs[H];
    __shared__ float zs[M];

    hs[t]       = (float)h_hi[(size_t)b * H + t]       + (float)h_lo[(size_t)b * H + t];
    hs[t + 256] = (float)h_hi[(size_t)b * H + 256 + t] + (float)h_lo[(size_t)b * H + 256 + t];
    __syncthreads();

    float acc = bh1[j * M + t];
    const float* w = Wh1 + (size_t)j * H * M + t;
#pragma unroll 8
    for (int k = 0; k < H; ++k) acc = fmaf(hs[k], w[(size_t)k * M], acc);

    zs[t] = gelu_exact(acc);
    __syncthreads();

    if (t < HOR) {
        float a = bh2[j * HOR + t];
        const float* w2 = Wh2 + (size_t)j * M * HOR + t;
        for (int m = 0; m < M; ++m) a = fmaf(zs[m], w2[(size_t)m * HOR], a);
        out[(size_t)b * HOR + t] = a;
    }
}

// ---------------------------------------------------------------------------
extern "C" void kernel_launch(void* const* d_in, const int* in_sizes, int n_in,
                              void* d_out, int out_size, void* d_ws, size_t ws_size,
                              hipStream_t stream)
{
    const float* x     = (const float*)d_in[0];
    const int*   joint = (const int*)  d_in[1];
    const float* Wp    = (const float*)d_in[2];
    const float* bp    = (const float*)d_in[3];
    const float* gamma = (const float*)d_in[4];
    const float* beta  = (const float*)d_in[5];
    const float* Wih0  = (const float*)d_in[6];
    const float* Whh0  = (const float*)d_in[7];
    const float* bih0  = (const float*)d_in[8];
    const float* bhh0  = (const float*)d_in[9];
    const float* Wih1  = (const float*)d_in[10];
    const float* Whh1  = (const float*)d_in[11];
    const float* bih1  = (const float*)d_in[12];
    const float* bhh1  = (const float*)d_in[13];
    const float* Wh1   = (const float*)d_in[14];
    const float* bh1   = (const float*)d_in[15];
    const float* Wh2   = (const float*)d_in[16];
    const float* bh2   = (const float*)d_in[17];
    float* out = (float*)d_out;

    char* base = (char*)d_ws;
    size_t off = 0;
    auto take = [&](size_t nbytes) -> void* {
        void* p = base + off;
        off = (off + nbytes + 255) & ~(size_t)255;
        return p;
    };

    RArgs a;
    a.W0hi = (bf16*)take((size_t)G * K0 * 2);
    a.W0lo = (bf16*)take((size_t)G * K0 * 2);
    a.W1hi = (bf16*)take((size_t)G * K1 * 2);
    a.W1lo = (bf16*)take((size_t)G * K1 * 2);
    a.bsum0 = (float*)take(G * 4);
    a.bsum1 = (float*)take(G * 4);

    const size_t states_off = off;
    for (int i = 0; i < 2; ++i) a.h0hi[i] = (bf16*)take((size_t)B * H * 2);
    for (int i = 0; i < 2; ++i) a.h0lo[i] = (bf16*)take((size_t)B * H * 2);
    for (int i = 0; i < 2; ++i) a.h1hi[i] = (bf16*)take((size_t)B * H * 2);
    for (int i = 0; i < 2; ++i) a.h1lo[i] = (bf16*)take((size_t)B * H * 2);
    a.bar = (unsigned int*)take(4 * 256);
    const size_t states_bytes = off - states_off;   // h bufs + bar -> zeroed

    bf16* ehi = (bf16*)take((size_t)L * B * P * 2);
    bf16* elo = (bf16*)take((size_t)L * B * P * 2);
    a.use_elo = (off <= ws_size) ? 1 : 0;
    if (!a.use_elo) elo = ehi;   // never read/written when use_elo==0
    a.ehi = ehi; a.elo = elo;

    prep_w0<<<dim3(3, G), 256, 0, stream>>>(Wih0, Whh0, (bf16*)a.W0hi, (bf16*)a.W0lo);
    prep_w1<<<dim3(4, G), 256, 0, stream>>>(Wih1, Whh1, (bf16*)a.W1hi, (bf16*)a.W1lo);
    prep_bias<<<8, 256, 0, stream>>>(bih0, bhh0, bih1, bhh1, (float*)a.bsum0, (float*)a.bsum1);
    hipMemsetAsync(base + states_off, 0, states_bytes, stream);
    emb_kernel<<<B * L, 256, 0, stream>>>(x, Wp, bp, gamma, beta, ehi, elo, a.use_elo);

    void* params[] = { &a };
    hipLaunchCooperativeKernel((void*)recurrence_kernel, dim3(256), dim3(256),
                               params, 0, stream);

    // final h1 (step 511) written at tick t=512 into buf[1-(512&1)] = buf 1
    head_kernel<<<B, 256, 0, stream>>>(a.h1hi[1], a.h1lo[1], joint, Wh1, bh1, Wh2, bh2, out);
}

// Round 7
// 18739.952 us; speedup vs baseline: 2.5932x; 1.3532x over previous
//
#include <hip/hip_runtime.h>
#include <math.h>

typedef __bf16 bf16;
typedef __attribute__((ext_vector_type(8))) __bf16 bf16x8;
typedef __attribute__((ext_vector_type(4))) float f32x4;

static constexpr int B = 256, L = 512, D = 64, P = 256, H = 512, M = 256, HOR = 9;
static constexpr int G = 2048;
static constexpr int K0 = P + H;      // 768
static constexpr int K1 = 2 * H;      // 1024
static constexpr float EPS = 1e-5f;
static constexpr int NB = 8;          // rolling A-prefetch depth (regs)
static constexpr int LDS_BYTES = 163840;   // W-hi(max 128K) + 2x16K A dbuf

#define MFMA(a, b, c) __builtin_amdgcn_mfma_f32_16x16x32_bf16((a), (b), (c), 0, 0, 0)

__device__ __forceinline__ float sigmoidf_(float x) { return 1.0f / (1.0f + expf(-x)); }
__device__ __forceinline__ float gelu_exact(float x) {
    return 0.5f * x * (1.0f + erff(x * 0.70710678118654752f));
}

// Device-coherent 16B load (2 x 8B agent-scope relaxed atomic loads -> sc1,
// reads the LLC past any stale per-XCD L2, pipelined by vmcnt scoreboarding).
__device__ __forceinline__ bf16x8 cload(const bf16* p) {
    union { unsigned long long u[2]; bf16x8 v; } r;
    const unsigned long long* q = (const unsigned long long*)p;
    r.u[0] = __hip_atomic_load(q,     __ATOMIC_RELAXED, __HIP_MEMORY_SCOPE_AGENT);
    r.u[1] = __hip_atomic_load(q + 1, __ATOMIC_RELAXED, __HIP_MEMORY_SCOPE_AGENT);
    return r.v;
}

// ---------------------------------------------------------------------------
// emb = gelu(LN(x@Wp+bp)) -> bf16 hi/lo, T-MAJOR: [(t*B + b)*P + p]
// ---------------------------------------------------------------------------
__global__ __launch_bounds__(256) void emb_kernel(
    const float* __restrict__ x, const float* __restrict__ Wp,
    const float* __restrict__ bp, const float* __restrict__ gamma,
    const float* __restrict__ beta, bf16* __restrict__ ehi,
    bf16* __restrict__ elo, int use_elo)
{
    const int row = blockIdx.x;          // b*L + t
    const int b   = row >> 9;
    const int t   = row & (L - 1);
    const int p   = threadIdx.x;
    __shared__ float xs[D];
    __shared__ float red[P];

    if (p < D) xs[p] = x[(size_t)row * D + p];
    __syncthreads();

    float acc = bp[p];
#pragma unroll
    for (int k = 0; k < D; ++k) acc = fmaf(xs[k], Wp[k * P + p], acc);

    red[p] = acc;
    __syncthreads();
    for (int s = 128; s > 0; s >>= 1) { if (p < s) red[p] += red[p + s]; __syncthreads(); }
    const float mu = red[0] * (1.0f / (float)P);
    __syncthreads();
    const float d = acc - mu;
    red[p] = d * d;
    __syncthreads();
    for (int s = 128; s > 0; s >>= 1) { if (p < s) red[p] += red[p + s]; __syncthreads(); }
    const float var = red[0] * (1.0f / (float)P);

    const float v = gelu_exact(gamma[p] * d * rsqrtf(var + EPS) + beta[p]);
    const size_t o = ((size_t)t * B + b) * P + p;
    const bf16 hh = (bf16)v;
    ehi[o] = hh;
    if (use_elo) elo[o] = (bf16)(v - (float)hh);
}

// ---------------------------------------------------------------------------
// weight prep in FRAG-LINEAR order: for (ng, S, wc, lane):
//   8 bf16 at W[g = wc*512 + ng*16 + (lane&15)][k = S*32 + (lane>>4)*8 ..+8]
// linear index = (((ng*(K/32) + S)*4 + wc)*64 + lane)*8
// ---------------------------------------------------------------------------
__global__ __launch_bounds__(64) void prep_w_frag(
    const float* __restrict__ Wih, const float* __restrict__ Whh, int Kih,
    bf16* __restrict__ hi, bf16* __restrict__ lo)
{
    const int ng = blockIdx.x, S = blockIdx.y, wc = blockIdx.z;
    const int lane = threadIdx.x;
    const int g = wc * 512 + ng * 16 + (lane & 15);
    const int kbase = S * 32 + (lane >> 4) * 8;
    const size_t out = ((((size_t)ng * gridDim.y + S) * 4 + wc) * 64 + lane) * 8;
#pragma unroll
    for (int e = 0; e < 8; ++e) {
        const int k = kbase + e;
        const float v = (k < Kih) ? Wih[(size_t)g * Kih + k]
                                  : Whh[(size_t)g * 512 + (k - Kih)];
        const bf16 h = (bf16)v;
        hi[out + e] = h;
        lo[out + e] = (bf16)(v - (float)h);
    }
}

__global__ __launch_bounds__(256) void prep_bias(
    const float* __restrict__ bih0, const float* __restrict__ bhh0,
    const float* __restrict__ bih1, const float* __restrict__ bhh1,
    float* __restrict__ bsum0, float* __restrict__ bsum1)
{
    const int g = blockIdx.x * 256 + threadIdx.x;   // grid.x = 8
    bsum0[g] = bih0[g] + bhh0[g];
    bsum1[g] = bih1[g] + bhh1[g];
}

// ---------------------------------------------------------------------------
// Persistent recurrence, 256 blocks x 1024 threads (16 waves, 4x4 frag grid).
// Block = 64 batch rows x 64 gate cols (16 j x 4 gates; wave wc owns gate wc).
// W-hi slice LDS-resident across all ticks; W-lo streamed (frag-order, L1/L2);
// A panel (emb/h hi+lo) delivered via rolling sc1 loads -> LDS chunk dbuf.
// ---------------------------------------------------------------------------
struct RArgs {
    int use_elo;
    const bf16 *ehi, *elo;
    const bf16 *W0hif, *W0lof, *W1hif, *W1lof;   // frag-linear
    const float *bsum0, *bsum1;
    bf16 *h0hi[2], *h0lo[2], *h1hi[2], *h1lo[2];
    unsigned int* bar;    // 4 counters, 256B apart
};

template <int NC, int LAYER>
__device__ __forceinline__ void tick_body(
    int tid, int lane, int wr, int wc,
    int half, int grow, int kin, int slot,
    const bf16* __restrict__ a0, const bf16* __restrict__ a1,
    char* lds, const bf16* __restrict__ wlo_blk,
    float bI0, float bI1, float bF0, float bF1,
    float bG0, float bG1, float bO0, float bO1,
    float& c0r, float& c1r,
    unsigned int* hw_hi, unsigned int* hw_lo,
    int m, int jp)
{
    constexpr int K0seg = (LAYER == 0) ? 256 : 512;
    constexpr int AS0   = (LAYER == 0) ? 256 : 512;

    const bf16* wlds = (const bf16*)lds;
    char* dbuf = lds + 131072;
    float (*Gs)[68] = (float(*)[68])(lds + 131072);

    auto cloadA = [&](int c) -> bf16x8 {
        const int kk = c * 64 + kin;
        const bf16* p = (kk < K0seg) ? (a0 + (size_t)grow * AS0 + kk)
                                     : (a1 + (size_t)grow * 512 + (kk - K0seg));
        return cload(p);
    };
    auto stageW = [&](const bf16x8& v, int pb) {
        *(bf16x8*)(dbuf + pb * 16384 + half * 8192 + slot * 16) = v;
    };

    f32x4 hh = {0.f,0.f,0.f,0.f}, hl = {0.f,0.f,0.f,0.f}, lh = {0.f,0.f,0.f,0.f};

    bf16x8 areg[NB];
#pragma unroll
    for (int i = 0; i < NB; ++i) areg[i] = cloadA(i);
    stageW(areg[0], 0);
    areg[0] = cloadA(NB);          // NB < NC always (12 or 16)
    __syncthreads();

#pragma unroll
    for (int c = 0; c < NC; ++c) {
        if (c + 1 < NC) {
            stageW(areg[(c + 1) % NB], (c + 1) & 1);
            if (c + 1 + NB < NC) areg[(c + 1) % NB] = cloadA(c + 1 + NB);
        }
        const char* bufc = dbuf + (c & 1) * 16384;
#pragma unroll
        for (int s2 = 0; s2 < 2; ++s2) {
            const int S = c * 2 + s2;
            bf16x8 Ahi = *(const bf16x8*)(bufc + ((s2 * 4 + wr) * 64 + lane) * 16);
            bf16x8 Alo = *(const bf16x8*)(bufc + 8192 + ((s2 * 4 + wr) * 64 + lane) * 16);
            bf16x8 Whi = *(const bf16x8*)((const char*)wlds + ((S * 4 + wc) * 64 + lane) * 16);
            bf16x8 Wlo = *(const bf16x8*)(wlo_blk + (size_t)((S * 4 + wc) * 64 + lane) * 8);
            hh = MFMA(Ahi, Whi, hh);
            lh = MFMA(Alo, Whi, lh);
            hl = MFMA(Ahi, Wlo, hl);
        }
        __syncthreads();
    }

    // park gates in Gs (C/D layout: col = lane&15, row = (lane>>4)*4 + r)
#pragma unroll
    for (int r = 0; r < 4; ++r) {
        const int row = wr * 16 + (lane >> 4) * 4 + r;
        const int col = wc * 16 + (lane & 15);
        Gs[row][col] = hh[r] + hl[r] + lh[r];
    }
    __syncthreads();

    if (tid < 512) {
        float hv0, hv1;
        {
            const float iraw = Gs[m][jp]      + bI0;
            const float fraw = Gs[m][16 + jp] + bF0;
            const float graw = Gs[m][32 + jp] + bG0;
            const float oraw = Gs[m][48 + jp] + bO0;
            const float cv = sigmoidf_(fraw) * c0r + sigmoidf_(iraw) * tanhf(graw);
            c0r = cv;
            hv0 = sigmoidf_(oraw) * tanhf(cv);
        }
        {
            const float iraw = Gs[m][jp + 1]      + bI1;
            const float fraw = Gs[m][16 + jp + 1] + bF1;
            const float graw = Gs[m][32 + jp + 1] + bG1;
            const float oraw = Gs[m][48 + jp + 1] + bO1;
            const float cv = sigmoidf_(fraw) * c1r + sigmoidf_(iraw) * tanhf(graw);
            c1r = cv;
            hv1 = sigmoidf_(oraw) * tanhf(cv);
        }
        union { unsigned int u; bf16 b[2]; } ph, pl;
        ph.b[0] = (bf16)hv0; ph.b[1] = (bf16)hv1;
        pl.b[0] = (bf16)(hv0 - (float)ph.b[0]);
        pl.b[1] = (bf16)(hv1 - (float)ph.b[1]);
        __hip_atomic_store(hw_hi, ph.u, __ATOMIC_RELAXED, __HIP_MEMORY_SCOPE_AGENT);
        __hip_atomic_store(hw_lo, pl.u, __ATOMIC_RELAXED, __HIP_MEMORY_SCOPE_AGENT);
    }
}

__global__ __launch_bounds__(1024) void recurrence_kernel(RArgs a)
{
    extern __shared__ __align__(16) char lds[];

    const int layer = blockIdx.x >> 7;
    const int idx = blockIdx.x & 127;
    const int mg = idx >> 5, ng = idx & 31;
    const int bm0 = mg * 64, j0 = ng * 16;

    const int tid  = threadIdx.x;
    const int lane = tid & 63;
    const int wid  = tid >> 6;
    const int wr = wid >> 2, wc = wid & 3;

    // staging constants: thread -> (half, row, k-quad) and LDS frag slot
    const int half  = tid >> 9;
    const int u     = tid & 511;
    const int row_s = u >> 3;
    const int kq8   = u & 7;
    const int s_loc = kq8 >> 2, k8 = kq8 & 3;
    const int slot  = ((s_loc * 4 + (row_s >> 4)) * 64) + k8 * 16 + (row_s & 15);
    const int grow  = bm0 + row_s;
    const int kin   = kq8 * 8;

    // stage W-hi slab into LDS once (frag-linear)
    {
        const bf16* whif = layer ? a.W1hif : a.W0hif;
        const bf16* wsrc = whif + (size_t)ng * (size_t)(layer ? 65536 : 49152);
        const int NW = layer ? 8 : 6;
        for (int i = 0; i < NW; ++i) {
            const int ix = i * 1024 + tid;
            ((bf16x8*)lds)[ix] = *(const bf16x8*)(wsrc + (size_t)ix * 8);
        }
    }
    __syncthreads();
    const bf16* wlo_blk = (layer ? a.W1lof : a.W0lof)
                          + (size_t)ng * (size_t)(layer ? 65536 : 49152);

    // pointwise ownership (threads 0..511): (m, jp..jp+1)
    const int m  = (tid >> 3) & 63;
    const int jp = (tid & 7) * 2;
    const int j  = j0 + jp;
    const float* bs = layer ? a.bsum1 : a.bsum0;
    const float bI0 = bs[j],        bI1 = bs[j + 1];
    const float bF0 = bs[512 + j],  bF1 = bs[512 + j + 1];
    const float bG0 = bs[1024 + j], bG1 = bs[1024 + j + 1];
    const float bO0 = bs[1536 + j], bO1 = bs[1536 + j + 1];
    float c0r = 0.f, c1r = 0.f;
    const size_t hix = (size_t)(bm0 + m) * H + j;   // 4B-aligned (j even)

    unsigned int* bar = a.bar + mg * 64;

    for (int t = 0; t <= L; ++t) {
        const int p0 = t & 1;
        const bool active = layer ? (t >= 1) : (t < L);

        if (active) {
            if (layer == 0) {
                const bf16* a0 = (half ? a.elo : a.ehi) + (size_t)t * B * P;
                const bf16* a1 = half ? a.h0lo[1 - p0] : a.h0hi[1 - p0];
                bf16* hwh = a.h0hi[p0];
                bf16* hwl = a.h0lo[p0];
                tick_body<12, 0>(tid, lane, wr, wc, half, grow, kin, slot,
                                 a0, a1, lds, wlo_blk,
                                 bI0, bI1, bF0, bF1, bG0, bG1, bO0, bO1,
                                 c0r, c1r,
                                 (unsigned int*)(hwh + hix),
                                 (unsigned int*)(hwl + hix), m, jp);
            } else {
                const bf16* a0 = half ? a.h0lo[1 - p0] : a.h0hi[1 - p0];  // h0[t-1]
                const bf16* a1 = half ? a.h1lo[p0]     : a.h1hi[p0];      // h1[t-2]
                bf16* hwh = a.h1hi[1 - p0];
                bf16* hwl = a.h1lo[1 - p0];
                tick_body<16, 1>(tid, lane, wr, wc, half, grow, kin, slot,
                                 a0, a1, lds, wlo_blk,
                                 bI0, bI1, bF0, bF1, bG0, bG1, bO0, bO1,
                                 c0r, c1r,
                                 (unsigned int*)(hwh + hix),
                                 (unsigned int*)(hwl + hix), m, jp);
            }
        }

        // ---- group barrier: 64 blocks of row-group mg; zero cache ops ----
        __syncthreads();   // drains vmcnt -> sc1 stores visible at LLC
        if (tid == 0) {
            __hip_atomic_fetch_add(bar, 1u, __ATOMIC_RELAXED, __HIP_MEMORY_SCOPE_AGENT);
            const unsigned int target = 64u * (unsigned)(t + 1);
            while (__hip_atomic_load(bar, __ATOMIC_RELAXED, __HIP_MEMORY_SCOPE_AGENT) < target)
                __builtin_amdgcn_s_sleep(1);
        }
        __syncthreads();
    }
}

// ---------------------------------------------------------------------------
// head: per batch row b, j = joint_index[b]
// ---------------------------------------------------------------------------
__global__ __launch_bounds__(256) void head_kernel(
    const bf16* __restrict__ h_hi, const bf16* __restrict__ h_lo,
    const int* __restrict__ joint_index,
    const float* __restrict__ Wh1, const float* __restrict__ bh1,
    const float* __restrict__ Wh2, const float* __restrict__ bh2,
    float* __restrict__ out)
{
    const int b = blockIdx.x;
    const int t = threadIdx.x;
    const int j = joint_index[b];
    __shared__ float hs[H];
    __shared__ float zs[M];

    hs[t]       = (float)h_hi[(size_t)b * H + t]       + (float)h_lo[(size_t)b * H + t];
    hs[t + 256] = (float)h_hi[(size_t)b * H + 256 + t] + (float)h_lo[(size_t)b * H + 256 + t];
    __syncthreads();

    float acc = bh1[j * M + t];
    const float* w = Wh1 + (size_t)j * H * M + t;
#pragma unroll 8
    for (int k = 0; k < H; ++k) acc = fmaf(hs[k], w[(size_t)k * M], acc);

    zs[t] = gelu_exact(acc);
    __syncthreads();

    if (t < HOR) {
        float a = bh2[j * HOR + t];
        const float* w2 = Wh2 + (size_t)j * M * HOR + t;
        for (int mm = 0; mm < M; ++mm) a = fmaf(zs[mm], w2[(size_t)mm * HOR], a);
        out[(size_t)b * HOR + t] = a;
    }
}

// ---------------------------------------------------------------------------
extern "C" void kernel_launch(void* const* d_in, const int* in_sizes, int n_in,
                              void* d_out, int out_size, void* d_ws, size_t ws_size,
                              hipStream_t stream)
{
    const float* x     = (const float*)d_in[0];
    const int*   joint = (const int*)  d_in[1];
    const float* Wp    = (const float*)d_in[2];
    const float* bp    = (const float*)d_in[3];
    const float* gamma = (const float*)d_in[4];
    const float* beta  = (const float*)d_in[5];
    const float* Wih0  = (const float*)d_in[6];
    const float* Whh0  = (const float*)d_in[7];
    const float* bih0  = (const float*)d_in[8];
    const float* bhh0  = (const float*)d_in[9];
    const float* Wih1  = (const float*)d_in[10];
    const float* Whh1  = (const float*)d_in[11];
    const float* bih1  = (const float*)d_in[12];
    const float* bhh1  = (const float*)d_in[13];
    const float* Wh1   = (const float*)d_in[14];
    const float* bh1   = (const float*)d_in[15];
    const float* Wh2   = (const float*)d_in[16];
    const float* bh2   = (const float*)d_in[17];
    float* out = (float*)d_out;

    char* base = (char*)d_ws;
    size_t off = 0;
    auto take = [&](size_t nbytes) -> void* {
        void* p = base + off;
        off = (off + nbytes + 255) & ~(size_t)255;
        return p;
    };

    RArgs a;
    a.W0hif = (bf16*)take((size_t)G * K0 * 2);
    a.W0lof = (bf16*)take((size_t)G * K0 * 2);
    a.W1hif = (bf16*)take((size_t)G * K1 * 2);
    a.W1lof = (bf16*)take((size_t)G * K1 * 2);
    a.bsum0 = (float*)take(G * 4);
    a.bsum1 = (float*)take(G * 4);

    const size_t states_off = off;
    for (int i = 0; i < 2; ++i) a.h0hi[i] = (bf16*)take((size_t)B * H * 2);
    for (int i = 0; i < 2; ++i) a.h0lo[i] = (bf16*)take((size_t)B * H * 2);
    for (int i = 0; i < 2; ++i) a.h1hi[i] = (bf16*)take((size_t)B * H * 2);
    for (int i = 0; i < 2; ++i) a.h1lo[i] = (bf16*)take((size_t)B * H * 2);
    a.bar = (unsigned int*)take(4 * 256);
    const size_t states_bytes = off - states_off;   // h bufs + bar -> zeroed

    bf16* ehi = (bf16*)take((size_t)L * B * P * 2);
    bf16* elo = (bf16*)take((size_t)L * B * P * 2);
    a.use_elo = (off <= ws_size) ? 1 : 0;
    if (!a.use_elo) elo = ehi;
    a.ehi = ehi; a.elo = elo;

    prep_w_frag<<<dim3(32, K0 / 32, 4), 64, 0, stream>>>(Wih0, Whh0, P,
                                                         (bf16*)a.W0hif, (bf16*)a.W0lof);
    prep_w_frag<<<dim3(32, K1 / 32, 4), 64, 0, stream>>>(Wih1, Whh1, H,
                                                         (bf16*)a.W1hif, (bf16*)a.W1lof);
    prep_bias<<<8, 256, 0, stream>>>(bih0, bhh0, bih1, bhh1,
                                     (float*)a.bsum0, (float*)a.bsum1);
    hipMemsetAsync(base + states_off, 0, states_bytes, stream);
    emb_kernel<<<B * L, 256, 0, stream>>>(x, Wp, bp, gamma, beta, ehi, elo, a.use_elo);

    hipFuncSetAttribute((const void*)recurrence_kernel,
                        hipFuncAttributeMaxDynamicSharedMemorySize, LDS_BYTES);
    void* params[] = { &a };
    hipLaunchCooperativeKernel((void*)recurrence_kernel, dim3(256), dim3(1024),
                               params, LDS_BYTES, stream);

    // final h1 (step 511) written at tick t=512 into buf[1-(512&1)] = buf 1
    head_kernel<<<B, 256, 0, stream>>>(a.h1hi[1], a.h1lo[1], joint, Wh1, bh1, Wh2, bh2, out);
}